// Round 3
// baseline (6241.787 us; speedup 1.0000x reference)
//
#include <hip/hip_runtime.h>
#include <hip/hip_bf16.h>
#include <stdint.h>

#define EMBED  512
#define HIDDEN 512
#define VOCAB  32000
#define BATCH  64
#define NPIX   196
#define MAXLEN 32

typedef float f32x4 __attribute__((ext_vector_type(4)));
typedef float f32x2 __attribute__((ext_vector_type(2)));

// ---------- helpers ----------
__device__ __forceinline__ unsigned long long pack_key(float v, int idx) {
    unsigned u = __float_as_uint(v);
    u = (u & 0x80000000u) ? ~u : (u | 0x80000000u);   // monotone sortable map
    return ((unsigned long long)u << 32) | (unsigned)(~(unsigned)idx); // smaller idx wins ties
}

// ---------- init: summary, h0, c0, zero out[:,0,:] ----------
__global__ __launch_bounds__(256) void init_kernel(
    const float* __restrict__ enc,
    const float* __restrict__ W_init_h, const float* __restrict__ b_init_h,
    const float* __restrict__ W_init_c, const float* __restrict__ b_init_c,
    float* __restrict__ h0, float* __restrict__ c0, float* __restrict__ out)
{
    __shared__ __align__(16) float ssum[HIDDEN];
    const int b = blockIdx.x, tid = threadIdx.x;

    // phase A: summary = mean over pixels
    for (int k = tid; k < HIDDEN; k += 256) {
        float s = 0.f;
        const float* p = enc + (size_t)b * NPIX * HIDDEN + k;
        for (int px = 0; px < NPIX; ++px) s += p[(size_t)px * HIDDEN];
        ssum[k] = s * (1.0f / NPIX);
    }
    __syncthreads();

    // phase B: h0 = summary @ W_init_h^T + b, c0 likewise
    for (int j = tid; j < HIDDEN; j += 256) {
        const float4* wh = (const float4*)(W_init_h + (size_t)j * HIDDEN);
        const float4* wc = (const float4*)(W_init_c + (size_t)j * HIDDEN);
        float ah = 0.f, ac = 0.f;
        for (int k4 = 0; k4 < HIDDEN / 4; ++k4) {
            float4 s4 = *(const float4*)&ssum[k4 * 4];
            float4 a = wh[k4], cc = wc[k4];
            ah += s4.x * a.x + s4.y * a.y + s4.z * a.z + s4.w * a.w;
            ac += s4.x * cc.x + s4.y * cc.y + s4.z * cc.z + s4.w * cc.w;
        }
        h0[b * HIDDEN + j] = ah + b_init_h[j];
        c0[b * HIDDEN + j] = ac + b_init_c[j];
    }

    // phase C: zero out[b][0][:]
    f32x4* o4 = (f32x4*)(out + (size_t)b * MAXLEN * VOCAB);
    f32x4 z = {0.f, 0.f, 0.f, 0.f};
    for (int i = tid; i < VOCAB / 4; i += 256) __builtin_nontemporal_store(z, &o4[i]);
}

// ---------- per-step LSTM cell: gates + update ----------
__global__ __launch_bounds__(256) void lstm_step(
    const float* __restrict__ emb,
    const float* __restrict__ W_ih, const float* __restrict__ b_ih,
    const float* __restrict__ W_hh, const float* __restrict__ b_hh,
    const int*  __restrict__ captions,
    const unsigned long long* __restrict__ tok_keys,   // buf[(t-1)&1], valid for t>0
    unsigned long long* __restrict__ reset_keys,       // buf[t&1] -> zero before fc_argmax
    const float* __restrict__ h_in,
    float* __restrict__ h_out,
    float* __restrict__ c_ws,
    int t)
{
    const int tid = threadIdx.x;
    if (blockIdx.x == 0 && tid < BATCH) reset_keys[tid] = 0ull;

    const int u0 = blockIdx.x * 2;          // 256 blocks x 2 hidden units
    const int b = tid >> 2, q = tid & 3;    // 64 batch rows x 4 gate quadrants

    int tok;
    if (t == 0) tok = captions[b * MAXLEN];
    else        tok = (int)(~(unsigned)(tok_keys[b] & 0xffffffffull));

    const float4* x4 = (const float4*)(emb + (size_t)tok * EMBED);
    const float4* h4 = (const float4*)(h_in + b * HIDDEN);
    const int j_0 = q * HIDDEN + u0;        // gate row index (uu = 0)
    const float4* wiA = (const float4*)(W_ih + (size_t)j_0 * EMBED);
    const float4* wiB = wiA + EMBED / 4;
    const float4* whA = (const float4*)(W_hh + (size_t)j_0 * HIDDEN);
    const float4* whB = whA + HIDDEN / 4;

    float a0 = 0.f, a1 = 0.f;
#pragma unroll 4
    for (int k4 = 0; k4 < EMBED / 4; ++k4) {
        float4 xv = x4[k4], hv = h4[k4];
        float4 wA = wiA[k4], wB = wiB[k4], vA = whA[k4], vB = whB[k4];
        a0 += xv.x * wA.x + xv.y * wA.y + xv.z * wA.z + xv.w * wA.w
            + hv.x * vA.x + hv.y * vA.y + hv.z * vA.z + hv.w * vA.w;
        a1 += xv.x * wB.x + xv.y * wB.y + xv.z * wB.z + xv.w * wB.w
            + hv.x * vB.x + hv.y * vB.y + hv.z * vB.z + hv.w * vB.w;
    }
    a0 += b_ih[j_0] + b_hh[j_0];
    a1 += b_ih[j_0 + 1] + b_hh[j_0 + 1];

    const int lane = tid & 63;
    const int base = lane & ~3;
#pragma unroll
    for (int uu = 0; uu < 2; ++uu) {
        float g  = (uu == 0) ? a0 : a1;
        float gi = __shfl(g, base + 0, 64);
        float gf = __shfl(g, base + 1, 64);
        float gg = __shfl(g, base + 2, 64);
        float go = __shfl(g, base + 3, 64);
        if (q == uu) {
            const int u = u0 + uu;
            float i_ = 1.f / (1.f + expf(-gi));
            float f_ = 1.f / (1.f + expf(-gf));
            float o_ = 1.f / (1.f + expf(-go));
            float g_ = tanhf(gg);
            float cv = c_ws[b * HIDDEN + u];
            float c2 = f_ * cv + i_ * g_;
            float h2 = o_ * tanhf(c2);
            c_ws[b * HIDDEN + u]  = c2;
            h_out[b * HIDDEN + u] = h2;
        }
    }
}

// ---------- per-step fc + argmax ----------
// 500 one-wave blocks; each wave computes the full 64-row x 64-col tile,
// Tm=Tn=8 register blocking. h and W staged TRANSPOSED [k][col] in LDS with
// stride 68 (16B-aligned b128 reads, 2-way-max bank aliasing, 8-way bcast).
__global__ __launch_bounds__(64) void fc_argmax(
    const float* __restrict__ h2,
    const float* __restrict__ W_fc,
    const float* __restrict__ b_fc,
    float* __restrict__ out,
    unsigned long long* __restrict__ keys,
    int t)
{
    __shared__ __align__(16) float Ht[64 * 68];
    __shared__ __align__(16) float Wt[64 * 68];

    const int lane = threadIdx.x;           // 0..63
    const int n0 = blockIdx.x * 64;         // column tile base
    const int r = lane >> 3, c = lane & 7;  // 8x8 thread grid

    float acc[8][8];
#pragma unroll
    for (int i = 0; i < 8; ++i)
#pragma unroll
        for (int j = 0; j < 8; ++j) acc[i][j] = 0.f;

    const f32x4* hrow = (const f32x4*)(h2 + (size_t)lane * EMBED);          // h row = lane
    const f32x4* wrow = (const f32x4*)(W_fc + (size_t)(n0 + lane) * EMBED); // W row = col n0+lane

    for (int kc = 0; kc < 8; ++kc) {        // K chunks of 64
        __syncthreads();
#pragma unroll
        for (int q = 0; q < 16; ++q) {
            f32x4 hv = hrow[kc * 16 + q];
            f32x4 wv = wrow[kc * 16 + q];
            const int k = q * 4;
#pragma unroll
            for (int e = 0; e < 4; ++e) {
                Ht[(k + e) * 68 + lane] = hv[e];
                Wt[(k + e) * 68 + lane] = wv[e];
            }
        }
        __syncthreads();
#pragma unroll 4
        for (int k = 0; k < 64; ++k) {
            f32x4 ha = *(const f32x4*)&Ht[k * 68 + r * 8];
            f32x4 hb = *(const f32x4*)&Ht[k * 68 + r * 8 + 4];
            f32x4 wa = *(const f32x4*)&Wt[k * 68 + c * 8];
            f32x4 wb = *(const f32x4*)&Wt[k * 68 + c * 8 + 4];
            float hh[8] = {ha[0], ha[1], ha[2], ha[3], hb[0], hb[1], hb[2], hb[3]};
            float ww[8] = {wa[0], wa[1], wa[2], wa[3], wb[0], wb[1], wb[2], wb[3]};
#pragma unroll
            for (int i = 0; i < 8; ++i)
#pragma unroll
                for (int j = 0; j < 8; ++j)
                    acc[i][j] += hh[i] * ww[j];
        }
    }

    // epilogue: bias, NT store, per-row argmax reduce (across the 8 c-lanes)
    const int cbase = n0 + c * 8;
    f32x4 b0 = *(const f32x4*)&b_fc[cbase];
    f32x4 b1 = *(const f32x4*)&b_fc[cbase + 4];
    float bb[8] = {b0[0], b0[1], b0[2], b0[3], b1[0], b1[1], b1[2], b1[3]};

#pragma unroll
    for (int i = 0; i < 8; ++i) {
        const int m = r * 8 + i;
        float v[8];
        unsigned long long km = 0ull;
#pragma unroll
        for (int j = 0; j < 8; ++j) {
            v[j] = acc[i][j] + bb[j];
            unsigned long long kk = pack_key(v[j], cbase + j);
            km = kk > km ? kk : km;
        }
        f32x4 s0 = {v[0], v[1], v[2], v[3]};
        f32x4 s1 = {v[4], v[5], v[6], v[7]};
        float* op = &out[(size_t)m * (MAXLEN * VOCAB) + (size_t)(t + 1) * VOCAB + cbase];
        __builtin_nontemporal_store(s0, (f32x4*)op);
        __builtin_nontemporal_store(s1, (f32x4*)(op + 4));
#pragma unroll
        for (int msk = 4; msk >= 1; msk >>= 1) {
            unsigned long long o = __shfl_xor(km, msk, 64);
            km = km > o ? km : o;
        }
        if (c == 0) atomicMax(&keys[m], km);
    }
}

extern "C" void kernel_launch(void* const* d_in, const int* in_sizes, int n_in,
                              void* d_out, int out_size, void* d_ws, size_t ws_size,
                              hipStream_t stream) {
    const float* enc       = (const float*)d_in[0];
    const int*   captions  = (const int*)  d_in[1];
    const float* emb       = (const float*)d_in[2];
    const float* W_ih      = (const float*)d_in[3];
    const float* b_ih      = (const float*)d_in[4];
    const float* W_hh      = (const float*)d_in[5];
    const float* b_hh      = (const float*)d_in[6];
    const float* W_fc      = (const float*)d_in[7];
    const float* b_fc      = (const float*)d_in[8];
    const float* W_init_h  = (const float*)d_in[9];
    const float* b_init_h  = (const float*)d_in[10];
    const float* W_init_c  = (const float*)d_in[11];
    const float* b_init_c  = (const float*)d_in[12];
    float* out = (float*)d_out;

    float* ws = (float*)d_ws;
    float* h0 = ws;                 // 64*512
    float* h1 = ws + 32768;         // 64*512
    float* c  = ws + 65536;         // 64*512
    unsigned long long* keys = (unsigned long long*)(ws + 98304); // 2*64 packed keys

    init_kernel<<<64, 256, 0, stream>>>(enc, W_init_h, b_init_h, W_init_c, b_init_c,
                                        h0, c, out);
    for (int t = 0; t < MAXLEN - 1; ++t) {
        float* hin  = (t & 1) ? h1 : h0;
        float* hout = (t & 1) ? h0 : h1;
        unsigned long long* kread  = keys + (((t + 1) & 1) * 64); // buf[(t-1)&1]
        unsigned long long* kwrite = keys + ((t & 1) * 64);       // buf[t&1]
        lstm_step<<<256, 256, 0, stream>>>(emb, W_ih, b_ih, W_hh, b_hh, captions,
                                           kread, kwrite, hin, hout, c, t);
        fc_argmax<<<500, 64, 0, stream>>>(hout, W_fc, b_fc, out, kwrite, t);
    }
}

// Round 4
// 4519.573 us; speedup vs baseline: 1.3811x; 1.3811x over previous
//
#include <hip/hip_runtime.h>
#include <hip/hip_bf16.h>
#include <stdint.h>

#define EMBED  512
#define HIDDEN 512
#define VOCAB  32000
#define BATCH  64
#define NPIX   196
#define MAXLEN 32

typedef float f32x4 __attribute__((ext_vector_type(4)));
typedef short bf16x8 __attribute__((ext_vector_type(8)));   // 8 bf16 = 4 VGPRs (guide-verified frag type)
typedef unsigned short ushort_t;

// ---------- helpers ----------
__device__ __forceinline__ unsigned long long pack_key(float v, int idx) {
    unsigned u = __float_as_uint(v);
    u = (u & 0x80000000u) ? ~u : (u | 0x80000000u);   // monotone sortable map
    return ((unsigned long long)u << 32) | (unsigned)(~(unsigned)idx); // smaller idx wins ties
}
__device__ __forceinline__ ushort_t f2bf(float x) {           // round-to-nearest-even
    unsigned u = __float_as_uint(x);
    unsigned r = (u + 0x7fffu + ((u >> 16) & 1u)) >> 16;
    return (ushort_t)r;
}
__device__ __forceinline__ float bf2f(ushort_t h) {
    return __uint_as_float(((unsigned)h) << 16);
}

// ---------- W_fc -> bf16 hi/lo split (once per call) ----------
__global__ __launch_bounds__(256) void wsplit_kernel(
    const float* __restrict__ W_fc, ushort_t* __restrict__ Whi, ushort_t* __restrict__ Wlo)
{
    const int nt4 = VOCAB * EMBED / 4;                 // 4,096,000 f32x4
    const int stride = gridDim.x * blockDim.x;
    for (int i = blockIdx.x * blockDim.x + threadIdx.x; i < nt4; i += stride) {
        f32x4 w = ((const f32x4*)W_fc)[i];
        ushort_t hi[4], lo[4];
#pragma unroll
        for (int e = 0; e < 4; ++e) {
            hi[e] = f2bf(w[e]);
            lo[e] = f2bf(w[e] - bf2f(hi[e]));
        }
        *(uint64_t*)&Whi[i * 4] = *(const uint64_t*)hi;
        *(uint64_t*)&Wlo[i * 4] = *(const uint64_t*)lo;
    }
}

// ---------- init: summary, h0, c0, zero out[:,0,:] ----------
__global__ __launch_bounds__(256) void init_kernel(
    const float* __restrict__ enc,
    const float* __restrict__ W_init_h, const float* __restrict__ b_init_h,
    const float* __restrict__ W_init_c, const float* __restrict__ b_init_c,
    float* __restrict__ h0, float* __restrict__ c0, float* __restrict__ out)
{
    __shared__ __align__(16) float ssum[HIDDEN];
    const int b = blockIdx.x, tid = threadIdx.x;

    for (int k = tid; k < HIDDEN; k += 256) {
        float s = 0.f;
        const float* p = enc + (size_t)b * NPIX * HIDDEN + k;
        for (int px = 0; px < NPIX; ++px) s += p[(size_t)px * HIDDEN];
        ssum[k] = s * (1.0f / NPIX);
    }
    __syncthreads();

    for (int j = tid; j < HIDDEN; j += 256) {
        const float4* wh = (const float4*)(W_init_h + (size_t)j * HIDDEN);
        const float4* wc = (const float4*)(W_init_c + (size_t)j * HIDDEN);
        float ah = 0.f, ac = 0.f;
        for (int k4 = 0; k4 < HIDDEN / 4; ++k4) {
            float4 s4 = *(const float4*)&ssum[k4 * 4];
            float4 a = wh[k4], cc = wc[k4];
            ah += s4.x * a.x + s4.y * a.y + s4.z * a.z + s4.w * a.w;
            ac += s4.x * cc.x + s4.y * cc.y + s4.z * cc.z + s4.w * cc.w;
        }
        h0[b * HIDDEN + j] = ah + b_init_h[j];
        c0[b * HIDDEN + j] = ac + b_init_c[j];
    }

    f32x4* o4 = (f32x4*)(out + (size_t)b * MAXLEN * VOCAB);
    f32x4 z = {0.f, 0.f, 0.f, 0.f};
    for (int i = tid; i < VOCAB / 4; i += 256) __builtin_nontemporal_store(z, &o4[i]);
}

// ---------- per-step LSTM cell: gates + update (+ bf16 split of h) ----------
__global__ __launch_bounds__(256) void lstm_step(
    const float* __restrict__ emb,
    const float* __restrict__ W_ih, const float* __restrict__ b_ih,
    const float* __restrict__ W_hh, const float* __restrict__ b_hh,
    const int*  __restrict__ captions,
    const unsigned long long* __restrict__ tok_keys,
    unsigned long long* __restrict__ reset_keys,
    const float* __restrict__ h_in,
    float* __restrict__ h_out,
    ushort_t* __restrict__ h_hi, ushort_t* __restrict__ h_lo,
    float* __restrict__ c_ws,
    int t)
{
    const int tid = threadIdx.x;
    if (blockIdx.x == 0 && tid < BATCH) reset_keys[tid] = 0ull;

    const int u0 = blockIdx.x * 2;
    const int b = tid >> 2, q = tid & 3;

    int tok;
    if (t == 0) tok = captions[b * MAXLEN];
    else        tok = (int)(~(unsigned)(tok_keys[b] & 0xffffffffull));

    const float4* x4 = (const float4*)(emb + (size_t)tok * EMBED);
    const float4* h4 = (const float4*)(h_in + b * HIDDEN);
    const int j_0 = q * HIDDEN + u0;
    const float4* wiA = (const float4*)(W_ih + (size_t)j_0 * EMBED);
    const float4* wiB = wiA + EMBED / 4;
    const float4* whA = (const float4*)(W_hh + (size_t)j_0 * HIDDEN);
    const float4* whB = whA + HIDDEN / 4;

    float a0 = 0.f, a1 = 0.f;
#pragma unroll 4
    for (int k4 = 0; k4 < EMBED / 4; ++k4) {
        float4 xv = x4[k4], hv = h4[k4];
        float4 wA = wiA[k4], wB = wiB[k4], vA = whA[k4], vB = whB[k4];
        a0 += xv.x * wA.x + xv.y * wA.y + xv.z * wA.z + xv.w * wA.w
            + hv.x * vA.x + hv.y * vA.y + hv.z * vA.z + hv.w * vA.w;
        a1 += xv.x * wB.x + xv.y * wB.y + xv.z * wB.z + xv.w * wB.w
            + hv.x * vB.x + hv.y * vB.y + hv.z * vB.z + hv.w * vB.w;
    }
    a0 += b_ih[j_0] + b_hh[j_0];
    a1 += b_ih[j_0 + 1] + b_hh[j_0 + 1];

    const int lane = tid & 63;
    const int base = lane & ~3;
#pragma unroll
    for (int uu = 0; uu < 2; ++uu) {
        float g  = (uu == 0) ? a0 : a1;
        float gi = __shfl(g, base + 0, 64);
        float gf = __shfl(g, base + 1, 64);
        float gg = __shfl(g, base + 2, 64);
        float go = __shfl(g, base + 3, 64);
        if (q == uu) {
            const int u = u0 + uu;
            float i_ = 1.f / (1.f + expf(-gi));
            float f_ = 1.f / (1.f + expf(-gf));
            float o_ = 1.f / (1.f + expf(-go));
            float g_ = tanhf(gg);
            float cv = c_ws[b * HIDDEN + u];
            float c2 = f_ * cv + i_ * g_;
            float h2 = o_ * tanhf(c2);
            c_ws[b * HIDDEN + u]  = c2;
            h_out[b * HIDDEN + u] = h2;
            ushort_t hh = f2bf(h2);
            h_hi[b * HIDDEN + u] = hh;
            h_lo[b * HIDDEN + u] = f2bf(h2 - bf2f(hh));
        }
    }
}

// ---------- per-step fc + argmax: bf16-split MFMA, no LDS ----------
// 500 one-wave blocks; wave computes 64 rows x 64 cols via 4x4 tiles of
// mfma_f32_16x16x32_bf16, 3 split-products per tile. A = h (row=lane&15),
// B = W_fc rows (col=lane&15), k-group = (lane>>4)*8 — consistent A/B k-map.
__global__ __launch_bounds__(64) void fc_argmax(
    const ushort_t* __restrict__ h_hi, const ushort_t* __restrict__ h_lo,
    const ushort_t* __restrict__ Whi,  const ushort_t* __restrict__ Wlo,
    const float* __restrict__ b_fc,
    float* __restrict__ out,
    unsigned long long* __restrict__ keys,
    int t)
{
    const int lane = threadIdx.x;
    const int r16 = lane & 15, g = lane >> 4;
    const int n0 = blockIdx.x * 64;

    f32x4 acc[4][4];
#pragma unroll
    for (int i = 0; i < 4; ++i)
#pragma unroll
        for (int j = 0; j < 4; ++j) acc[i][j] = (f32x4){0.f, 0.f, 0.f, 0.f};

    const ushort_t* ha = h_hi + (size_t)r16 * EMBED + g * 8;
    const ushort_t* la = h_lo + (size_t)r16 * EMBED + g * 8;
    const ushort_t* hb = Whi + (size_t)(n0 + r16) * EMBED + g * 8;
    const ushort_t* lb = Wlo + (size_t)(n0 + r16) * EMBED + g * 8;

    for (int kb = 0; kb < 16; ++kb) {
        const int ko = kb * 32;
        bf16x8 Ah[4], Al[4], Bh[4], Bl[4];
#pragma unroll
        for (int mt = 0; mt < 4; ++mt) {
            Ah[mt] = *(const bf16x8*)(ha + (size_t)mt * 16 * EMBED + ko);
            Al[mt] = *(const bf16x8*)(la + (size_t)mt * 16 * EMBED + ko);
        }
#pragma unroll
        for (int nt = 0; nt < 4; ++nt) {
            Bh[nt] = *(const bf16x8*)(hb + (size_t)nt * 16 * EMBED + ko);
            Bl[nt] = *(const bf16x8*)(lb + (size_t)nt * 16 * EMBED + ko);
        }
#pragma unroll
        for (int mt = 0; mt < 4; ++mt)
#pragma unroll
            for (int nt = 0; nt < 4; ++nt) {
                acc[mt][nt] = __builtin_amdgcn_mfma_f32_16x16x32_bf16(Al[mt], Bh[nt], acc[mt][nt], 0, 0, 0);
                acc[mt][nt] = __builtin_amdgcn_mfma_f32_16x16x32_bf16(Ah[mt], Bl[nt], acc[mt][nt], 0, 0, 0);
                acc[mt][nt] = __builtin_amdgcn_mfma_f32_16x16x32_bf16(Ah[mt], Bh[nt], acc[mt][nt], 0, 0, 0);
            }
    }

    // epilogue: bias, NT store, per-row argmax. C/D map: col=lane&15, row=g*4+reg.
    float bias[4];
#pragma unroll
    for (int nt = 0; nt < 4; ++nt) bias[nt] = b_fc[n0 + nt * 16 + r16];

#pragma unroll
    for (int mt = 0; mt < 4; ++mt)
#pragma unroll
        for (int reg = 0; reg < 4; ++reg) {
            const int row = mt * 16 + g * 4 + reg;
            float* op = &out[(size_t)row * (MAXLEN * VOCAB) + (size_t)(t + 1) * VOCAB];
            unsigned long long km = 0ull;
#pragma unroll
            for (int nt = 0; nt < 4; ++nt) {
                const int col = n0 + nt * 16 + r16;
                float v = acc[mt][nt][reg] + bias[nt];
                __builtin_nontemporal_store(v, op + col);
                unsigned long long kk = pack_key(v, col);
                km = kk > km ? kk : km;
            }
#pragma unroll
            for (int msk = 8; msk >= 1; msk >>= 1) {
                unsigned long long o = __shfl_xor(km, msk, 64);
                km = km > o ? km : o;
            }
            if (r16 == 0) atomicMax(&keys[row], km);
        }
}

extern "C" void kernel_launch(void* const* d_in, const int* in_sizes, int n_in,
                              void* d_out, int out_size, void* d_ws, size_t ws_size,
                              hipStream_t stream) {
    const float* enc       = (const float*)d_in[0];
    const int*   captions  = (const int*)  d_in[1];
    const float* emb       = (const float*)d_in[2];
    const float* W_ih      = (const float*)d_in[3];
    const float* b_ih      = (const float*)d_in[4];
    const float* W_hh      = (const float*)d_in[5];
    const float* b_hh      = (const float*)d_in[6];
    const float* W_fc      = (const float*)d_in[7];
    const float* b_fc      = (const float*)d_in[8];
    const float* W_init_h  = (const float*)d_in[9];
    const float* b_init_h  = (const float*)d_in[10];
    const float* W_init_c  = (const float*)d_in[11];
    const float* b_init_c  = (const float*)d_in[12];
    float* out = (float*)d_out;

    float* ws = (float*)d_ws;
    float* h0 = ws;                                         // 64*512 f32
    float* h1 = ws + 32768;                                 // 64*512 f32
    float* c  = ws + 65536;                                 // 64*512 f32
    unsigned long long* keys = (unsigned long long*)(ws + 98304);   // 2*64 u64 (256 f32)
    ushort_t* h_hi = (ushort_t*)(ws + 98560);               // 64*512 bf16 (16384 f32)
    ushort_t* h_lo = (ushort_t*)(ws + 114944);              // 64*512 bf16
    ushort_t* Whi  = (ushort_t*)(ws + 131328);              // 32000*512 bf16 (8.192M f32)
    ushort_t* Wlo  = (ushort_t*)(ws + 8323328);             // 32000*512 bf16

    wsplit_kernel<<<4096, 256, 0, stream>>>(W_fc, Whi, Wlo);
    init_kernel<<<64, 256, 0, stream>>>(enc, W_init_h, b_init_h, W_init_c, b_init_c,
                                        h0, c, out);
    for (int t = 0; t < MAXLEN - 1; ++t) {
        float* hin  = (t & 1) ? h1 : h0;
        float* hout = (t & 1) ? h0 : h1;
        unsigned long long* kread  = keys + (((t + 1) & 1) * 64);
        unsigned long long* kwrite = keys + ((t & 1) * 64);
        lstm_step<<<256, 256, 0, stream>>>(emb, W_ih, b_ih, W_hh, b_hh, captions,
                                           kread, kwrite, hin, hout, h_hi, h_lo, c, t);
        fc_argmax<<<500, 64, 0, stream>>>(h_hi, h_lo, Whi, Wlo, b_fc, out, kwrite, t);
    }
}

// Round 5
// 3313.434 us; speedup vs baseline: 1.8838x; 1.3640x over previous
//
#include <hip/hip_runtime.h>
#include <hip/hip_bf16.h>
#include <stdint.h>

#define EMBED  512
#define HIDDEN 512
#define VOCAB  32000
#define BATCH  64
#define NPIX   196
#define MAXLEN 32
#define NBLK_FC 500

typedef float f32x4 __attribute__((ext_vector_type(4)));
typedef short bf16x8 __attribute__((ext_vector_type(8)));
typedef unsigned short ushort_t;

// ---------- helpers ----------
__device__ __forceinline__ unsigned long long pack_key(float v, int idx) {
    unsigned u = __float_as_uint(v);
    u = (u & 0x80000000u) ? ~u : (u | 0x80000000u);   // monotone sortable map
    return ((unsigned long long)u << 32) | (unsigned)(~(unsigned)idx); // smaller idx wins ties
}
__device__ __forceinline__ ushort_t f2bf(float x) {           // round-to-nearest-even
    unsigned u = __float_as_uint(x);
    unsigned r = (u + 0x7fffu + ((u >> 16) & 1u)) >> 16;
    return (ushort_t)r;
}
__device__ __forceinline__ float bf2f(ushort_t h) {
    return __uint_as_float(((unsigned)h) << 16);
}

// ---------- W_fc -> bf16 hi/lo split (once per call) ----------
__global__ __launch_bounds__(256) void wsplit_kernel(
    const float* __restrict__ W_fc, ushort_t* __restrict__ Whi, ushort_t* __restrict__ Wlo)
{
    const int nt4 = VOCAB * EMBED / 4;
    const int stride = gridDim.x * blockDim.x;
    for (int i = blockIdx.x * blockDim.x + threadIdx.x; i < nt4; i += stride) {
        f32x4 w = ((const f32x4*)W_fc)[i];
        ushort_t hi[4], lo[4];
#pragma unroll
        for (int e = 0; e < 4; ++e) {
            hi[e] = f2bf(w[e]);
            lo[e] = f2bf(w[e] - bf2f(hi[e]));
        }
        *(uint64_t*)&Whi[i * 4] = *(const uint64_t*)hi;
        *(uint64_t*)&Wlo[i * 4] = *(const uint64_t*)lo;
    }
}

// ---------- init: summary, h0, c0, zero out[:,0,:] ----------
__global__ __launch_bounds__(256) void init_kernel(
    const float* __restrict__ enc,
    const float* __restrict__ W_init_h, const float* __restrict__ b_init_h,
    const float* __restrict__ W_init_c, const float* __restrict__ b_init_c,
    float* __restrict__ h0, float* __restrict__ c0, float* __restrict__ out)
{
    __shared__ __align__(16) float ssum[HIDDEN];
    const int b = blockIdx.x, tid = threadIdx.x;

    for (int k = tid; k < HIDDEN; k += 256) {
        float s = 0.f;
        const float* p = enc + (size_t)b * NPIX * HIDDEN + k;
        for (int px = 0; px < NPIX; ++px) s += p[(size_t)px * HIDDEN];
        ssum[k] = s * (1.0f / NPIX);
    }
    __syncthreads();

    for (int j = tid; j < HIDDEN; j += 256) {
        const float4* wh = (const float4*)(W_init_h + (size_t)j * HIDDEN);
        const float4* wc = (const float4*)(W_init_c + (size_t)j * HIDDEN);
        float ah = 0.f, ac = 0.f;
        for (int k4 = 0; k4 < HIDDEN / 4; ++k4) {
            float4 s4 = *(const float4*)&ssum[k4 * 4];
            float4 a = wh[k4], cc = wc[k4];
            ah += s4.x * a.x + s4.y * a.y + s4.z * a.z + s4.w * a.w;
            ac += s4.x * cc.x + s4.y * cc.y + s4.z * cc.z + s4.w * cc.w;
        }
        h0[b * HIDDEN + j] = ah + b_init_h[j];
        c0[b * HIDDEN + j] = ac + b_init_c[j];
    }

    f32x4* o4 = (f32x4*)(out + (size_t)b * MAXLEN * VOCAB);
    f32x4 z = {0.f, 0.f, 0.f, 0.f};
    for (int i = tid; i < VOCAB / 4; i += 256) __builtin_nontemporal_store(z, &o4[i]);
}

// ---------- per-step LSTM cell: gates + update (+ bf16 split of h) ----------
__global__ __launch_bounds__(256) void lstm_step(
    const float* __restrict__ emb,
    const float* __restrict__ W_ih, const float* __restrict__ b_ih,
    const float* __restrict__ W_hh, const float* __restrict__ b_hh,
    const int*  __restrict__ captions,
    const int*  __restrict__ toks,            // from argmax_reduce, valid for t>0
    const float* __restrict__ h_in,
    float* __restrict__ h_out,
    ushort_t* __restrict__ h_hi, ushort_t* __restrict__ h_lo,
    float* __restrict__ c_ws,
    int t)
{
    const int tid = threadIdx.x;
    const int u0 = blockIdx.x * 2;
    const int b = tid >> 2, q = tid & 3;

    int tok;
    if (t == 0) tok = captions[b * MAXLEN];
    else        tok = toks[b];

    const float4* x4 = (const float4*)(emb + (size_t)tok * EMBED);
    const float4* h4 = (const float4*)(h_in + b * HIDDEN);
    const int j_0 = q * HIDDEN + u0;
    const float4* wiA = (const float4*)(W_ih + (size_t)j_0 * EMBED);
    const float4* wiB = wiA + EMBED / 4;
    const float4* whA = (const float4*)(W_hh + (size_t)j_0 * HIDDEN);
    const float4* whB = whA + HIDDEN / 4;

    float a0 = 0.f, a1 = 0.f;
#pragma unroll 4
    for (int k4 = 0; k4 < EMBED / 4; ++k4) {
        float4 xv = x4[k4], hv = h4[k4];
        float4 wA = wiA[k4], wB = wiB[k4], vA = whA[k4], vB = whB[k4];
        a0 += xv.x * wA.x + xv.y * wA.y + xv.z * wA.z + xv.w * wA.w
            + hv.x * vA.x + hv.y * vA.y + hv.z * vA.z + hv.w * vA.w;
        a1 += xv.x * wB.x + xv.y * wB.y + xv.z * wB.z + xv.w * wB.w
            + hv.x * vB.x + hv.y * vB.y + hv.z * vB.z + hv.w * vB.w;
    }
    a0 += b_ih[j_0] + b_hh[j_0];
    a1 += b_ih[j_0 + 1] + b_hh[j_0 + 1];

    const int lane = tid & 63;
    const int base = lane & ~3;
#pragma unroll
    for (int uu = 0; uu < 2; ++uu) {
        float g  = (uu == 0) ? a0 : a1;
        float gi = __shfl(g, base + 0, 64);
        float gf = __shfl(g, base + 1, 64);
        float gg = __shfl(g, base + 2, 64);
        float go = __shfl(g, base + 3, 64);
        if (q == uu) {
            const int u = u0 + uu;
            float i_ = 1.f / (1.f + expf(-gi));
            float f_ = 1.f / (1.f + expf(-gf));
            float o_ = 1.f / (1.f + expf(-go));
            float g_ = tanhf(gg);
            float cv = c_ws[b * HIDDEN + u];
            float c2 = f_ * cv + i_ * g_;
            float h2 = o_ * tanhf(c2);
            c_ws[b * HIDDEN + u]  = c2;
            h_out[b * HIDDEN + u] = h2;
            ushort_t hh = f2bf(h2);
            h_hi[b * HIDDEN + u] = hh;
            h_lo[b * HIDDEN + u] = f2bf(h2 - bf2f(hh));
        }
    }
}

// ---------- per-step fc: bf16-split MFMA, no LDS, NO atomics ----------
// 500 one-wave blocks; wave computes 64 rows x 64 cols via 4x4 tiles of
// mfma_f32_16x16x32_bf16, 3 split-products per tile. Per-row max key goes to
// a private slot part[block][row] — plain stores, no device-atomic serialization.
__global__ __launch_bounds__(64) void fc_argmax(
    const ushort_t* __restrict__ h_hi, const ushort_t* __restrict__ h_lo,
    const ushort_t* __restrict__ Whi,  const ushort_t* __restrict__ Wlo,
    const float* __restrict__ b_fc,
    float* __restrict__ out,
    unsigned long long* __restrict__ part,
    int t)
{
    const int lane = threadIdx.x;
    const int r16 = lane & 15, g = lane >> 4;
    const int n0 = blockIdx.x * 64;

    f32x4 acc[4][4];
#pragma unroll
    for (int i = 0; i < 4; ++i)
#pragma unroll
        for (int j = 0; j < 4; ++j) acc[i][j] = (f32x4){0.f, 0.f, 0.f, 0.f};

    const ushort_t* ha = h_hi + (size_t)r16 * EMBED + g * 8;
    const ushort_t* la = h_lo + (size_t)r16 * EMBED + g * 8;
    const ushort_t* hb = Whi + (size_t)(n0 + r16) * EMBED + g * 8;
    const ushort_t* lb = Wlo + (size_t)(n0 + r16) * EMBED + g * 8;

    for (int kb = 0; kb < 16; ++kb) {
        const int ko = kb * 32;
        bf16x8 Ah[4], Al[4], Bh[4], Bl[4];
#pragma unroll
        for (int mt = 0; mt < 4; ++mt) {
            Ah[mt] = *(const bf16x8*)(ha + (size_t)mt * 16 * EMBED + ko);
            Al[mt] = *(const bf16x8*)(la + (size_t)mt * 16 * EMBED + ko);
        }
#pragma unroll
        for (int nt = 0; nt < 4; ++nt) {
            Bh[nt] = *(const bf16x8*)(hb + (size_t)nt * 16 * EMBED + ko);
            Bl[nt] = *(const bf16x8*)(lb + (size_t)nt * 16 * EMBED + ko);
        }
#pragma unroll
        for (int mt = 0; mt < 4; ++mt)
#pragma unroll
            for (int nt = 0; nt < 4; ++nt) {
                acc[mt][nt] = __builtin_amdgcn_mfma_f32_16x16x32_bf16(Al[mt], Bh[nt], acc[mt][nt], 0, 0, 0);
                acc[mt][nt] = __builtin_amdgcn_mfma_f32_16x16x32_bf16(Ah[mt], Bl[nt], acc[mt][nt], 0, 0, 0);
                acc[mt][nt] = __builtin_amdgcn_mfma_f32_16x16x32_bf16(Ah[mt], Bh[nt], acc[mt][nt], 0, 0, 0);
            }
    }

    // epilogue: bias, NT store, per-row max-key -> private slot (no atomics)
    float bias[4];
#pragma unroll
    for (int nt = 0; nt < 4; ++nt) bias[nt] = b_fc[n0 + nt * 16 + r16];

    unsigned long long* myslot = part + (size_t)blockIdx.x * BATCH;

#pragma unroll
    for (int mt = 0; mt < 4; ++mt)
#pragma unroll
        for (int reg = 0; reg < 4; ++reg) {
            const int row = mt * 16 + g * 4 + reg;
            float* op = &out[(size_t)row * (MAXLEN * VOCAB) + (size_t)(t + 1) * VOCAB];
            unsigned long long km = 0ull;
#pragma unroll
            for (int nt = 0; nt < 4; ++nt) {
                const int col = n0 + nt * 16 + r16;
                float v = acc[mt][nt][reg] + bias[nt];
                __builtin_nontemporal_store(v, op + col);
                unsigned long long kk = pack_key(v, col);
                km = kk > km ? kk : km;
            }
#pragma unroll
            for (int msk = 8; msk >= 1; msk >>= 1) {
                unsigned long long o = __shfl_xor(km, msk, 64);
                km = km > o ? km : o;
            }
            if (r16 == 0) myslot[row] = km;   // 4 lanes (g groups), 4 distinct rows
        }
}

// ---------- per-step argmax reduction: one wave per batch row ----------
__global__ __launch_bounds__(64) void argmax_reduce(
    const unsigned long long* __restrict__ part, int* __restrict__ toks)
{
    const int row = blockIdx.x, lane = threadIdx.x;
    unsigned long long km = 0ull;
    for (int blk = lane; blk < NBLK_FC; blk += 64) {
        unsigned long long k = part[(size_t)blk * BATCH + row];
        km = k > km ? k : km;
    }
#pragma unroll
    for (int msk = 32; msk >= 1; msk >>= 1) {
        unsigned long long o = __shfl_xor(km, msk, 64);
        km = km > o ? km : o;
    }
    if (lane == 0) toks[row] = (int)(~(unsigned)(km & 0xffffffffull));
}

extern "C" void kernel_launch(void* const* d_in, const int* in_sizes, int n_in,
                              void* d_out, int out_size, void* d_ws, size_t ws_size,
                              hipStream_t stream) {
    const float* enc       = (const float*)d_in[0];
    const int*   captions  = (const int*)  d_in[1];
    const float* emb       = (const float*)d_in[2];
    const float* W_ih      = (const float*)d_in[3];
    const float* b_ih      = (const float*)d_in[4];
    const float* W_hh      = (const float*)d_in[5];
    const float* b_hh      = (const float*)d_in[6];
    const float* W_fc      = (const float*)d_in[7];
    const float* b_fc      = (const float*)d_in[8];
    const float* W_init_h  = (const float*)d_in[9];
    const float* b_init_h  = (const float*)d_in[10];
    const float* W_init_c  = (const float*)d_in[11];
    const float* b_init_c  = (const float*)d_in[12];
    float* out = (float*)d_out;

    float* ws = (float*)d_ws;
    float* h0 = ws;                                          // 32768 f32
    float* h1 = ws + 32768;                                  // 32768 f32
    float* c  = ws + 65536;                                  // 32768 f32
    int* toks = (int*)(ws + 98304);                          // 64 int
    ushort_t* h_hi = (ushort_t*)(ws + 98560);                // 64*512 bf16
    ushort_t* h_lo = (ushort_t*)(ws + 114944);               // 64*512 bf16
    unsigned long long* part = (unsigned long long*)(ws + 131328); // 500*64 u64 = 64000 f32
    ushort_t* Whi  = (ushort_t*)(ws + 195328);               // 32000*512 bf16
    ushort_t* Wlo  = (ushort_t*)(ws + 8387328);              // 32000*512 bf16

    wsplit_kernel<<<4096, 256, 0, stream>>>(W_fc, Whi, Wlo);
    init_kernel<<<64, 256, 0, stream>>>(enc, W_init_h, b_init_h, W_init_c, b_init_c,
                                        h0, c, out);
    for (int t = 0; t < MAXLEN - 1; ++t) {
        float* hin  = (t & 1) ? h1 : h0;
        float* hout = (t & 1) ? h0 : h1;
        lstm_step<<<256, 256, 0, stream>>>(emb, W_ih, b_ih, W_hh, b_hh, captions,
                                           toks, hin, hout, h_hi, h_lo, c, t);
        fc_argmax<<<NBLK_FC, 64, 0, stream>>>(h_hi, h_lo, Whi, Wlo, b_fc, out, part, t);
        if (t < MAXLEN - 2)
            argmax_reduce<<<64, 64, 0, stream>>>(part, toks);
    }
}

// Round 6
// 3242.786 us; speedup vs baseline: 1.9248x; 1.0218x over previous
//
#include <hip/hip_runtime.h>
#include <hip/hip_bf16.h>
#include <stdint.h>

#define EMBED  512
#define HIDDEN 512
#define VOCAB  32000
#define BATCH  64
#define NPIX   196
#define MAXLEN 32
#define NTILE  500      // 64-col fc tiles
#define PSTRIDE 512     // part row stride (u64)

typedef float f32x4 __attribute__((ext_vector_type(4)));
typedef short bf16x8 __attribute__((ext_vector_type(8)));
typedef unsigned short ushort_t;

// ---------- helpers ----------
__device__ __forceinline__ unsigned long long pack_key(float v, int idx) {
    unsigned u = __float_as_uint(v);
    u = (u & 0x80000000u) ? ~u : (u | 0x80000000u);   // monotone sortable map
    return ((unsigned long long)u << 32) | (unsigned)(~(unsigned)idx); // smaller idx wins ties
}
__device__ __forceinline__ ushort_t f2bf(float x) {           // round-to-nearest-even
    unsigned u = __float_as_uint(x);
    unsigned r = (u + 0x7fffu + ((u >> 16) & 1u)) >> 16;
    return (ushort_t)r;
}
__device__ __forceinline__ float bf2f(ushort_t h) {
    return __uint_as_float(((unsigned)h) << 16);
}

// ---------- W_fc -> bf16 hi/lo split (once per call) ----------
__global__ __launch_bounds__(256) void wsplit_kernel(
    const float* __restrict__ W_fc, ushort_t* __restrict__ Whi, ushort_t* __restrict__ Wlo)
{
    const int nt4 = VOCAB * EMBED / 4;
    const int stride = gridDim.x * blockDim.x;
    for (int i = blockIdx.x * blockDim.x + threadIdx.x; i < nt4; i += stride) {
        f32x4 w = ((const f32x4*)W_fc)[i];
        ushort_t hi[4], lo[4];
#pragma unroll
        for (int e = 0; e < 4; ++e) {
            hi[e] = f2bf(w[e]);
            lo[e] = f2bf(w[e] - bf2f(hi[e]));
        }
        *(uint64_t*)&Whi[i * 4] = *(const uint64_t*)hi;
        *(uint64_t*)&Wlo[i * 4] = *(const uint64_t*)lo;
    }
}

// ---------- init: summary, h0, c0, zero out[:,0,:] ----------
__global__ __launch_bounds__(256) void init_kernel(
    const float* __restrict__ enc,
    const float* __restrict__ W_init_h, const float* __restrict__ b_init_h,
    const float* __restrict__ W_init_c, const float* __restrict__ b_init_c,
    float* __restrict__ h0, float* __restrict__ c0, float* __restrict__ out)
{
    __shared__ __align__(16) float ssum[HIDDEN];
    const int b = blockIdx.x, tid = threadIdx.x;

    for (int k = tid; k < HIDDEN; k += 256) {
        float s = 0.f;
        const float* p = enc + (size_t)b * NPIX * HIDDEN + k;
        for (int px = 0; px < NPIX; ++px) s += p[(size_t)px * HIDDEN];
        ssum[k] = s * (1.0f / NPIX);
    }
    __syncthreads();

    for (int j = tid; j < HIDDEN; j += 256) {
        const float4* wh = (const float4*)(W_init_h + (size_t)j * HIDDEN);
        const float4* wc = (const float4*)(W_init_c + (size_t)j * HIDDEN);
        float ah = 0.f, ac = 0.f;
        for (int k4 = 0; k4 < HIDDEN / 4; ++k4) {
            float4 s4 = *(const float4*)&ssum[k4 * 4];
            float4 a = wh[k4], cc = wc[k4];
            ah += s4.x * a.x + s4.y * a.y + s4.z * a.z + s4.w * a.w;
            ac += s4.x * cc.x + s4.y * cc.y + s4.z * cc.z + s4.w * cc.w;
        }
        h0[b * HIDDEN + j] = ah + b_init_h[j];
        c0[b * HIDDEN + j] = ac + b_init_c[j];
    }

    f32x4* o4 = (f32x4*)(out + (size_t)b * MAXLEN * VOCAB);
    f32x4 z = {0.f, 0.f, 0.f, 0.f};
    for (int i = tid; i < VOCAB / 4; i += 256) __builtin_nontemporal_store(z, &o4[i]);
}

// ---------- per-step LSTM cell (argmax-reduce folded in) ----------
__global__ __launch_bounds__(256) void lstm_step(
    const float* __restrict__ emb,
    const float* __restrict__ W_ih, const float* __restrict__ b_ih,
    const float* __restrict__ W_hh, const float* __restrict__ b_hh,
    const int*  __restrict__ captions,
    const unsigned long long* __restrict__ part,   // [64][PSTRIDE], valid for t>0
    const float* __restrict__ h_in,
    float* __restrict__ h_out,
    ushort_t* __restrict__ h_hi, ushort_t* __restrict__ h_lo,
    float* __restrict__ c_ws,
    int t)
{
    const int tid = threadIdx.x;
    const int u0 = blockIdx.x * 2;
    const int b = tid >> 2, q = tid & 3;

    int tok;
    if (t == 0) {
        tok = captions[b * MAXLEN];
    } else {
        // per-block redundant reduce of this row's 500 partial keys
        const unsigned long long* pr = part + (size_t)b * PSTRIDE + q * 125;
        unsigned long long km = 0ull;
#pragma unroll 5
        for (int i = 0; i < 125; ++i) {
            unsigned long long k = pr[i];
            km = k > km ? k : km;
        }
        unsigned long long o1 = __shfl_xor(km, 1, 64); km = km > o1 ? km : o1;
        unsigned long long o2 = __shfl_xor(km, 2, 64); km = km > o2 ? km : o2;
        tok = (int)(~(unsigned)(km & 0xffffffffull));
    }

    const float4* x4 = (const float4*)(emb + (size_t)tok * EMBED);
    const float4* h4 = (const float4*)(h_in + b * HIDDEN);
    const int j_0 = q * HIDDEN + u0;
    const float4* wiA = (const float4*)(W_ih + (size_t)j_0 * EMBED);
    const float4* wiB = wiA + EMBED / 4;
    const float4* whA = (const float4*)(W_hh + (size_t)j_0 * HIDDEN);
    const float4* whB = whA + HIDDEN / 4;

    float a0 = 0.f, a1 = 0.f;
#pragma unroll 4
    for (int k4 = 0; k4 < EMBED / 4; ++k4) {
        float4 xv = x4[k4], hv = h4[k4];
        float4 wA = wiA[k4], wB = wiB[k4], vA = whA[k4], vB = whB[k4];
        a0 += xv.x * wA.x + xv.y * wA.y + xv.z * wA.z + xv.w * wA.w
            + hv.x * vA.x + hv.y * vA.y + hv.z * vA.z + hv.w * vA.w;
        a1 += xv.x * wB.x + xv.y * wB.y + xv.z * wB.z + xv.w * wB.w
            + hv.x * vB.x + hv.y * vB.y + hv.z * vB.z + hv.w * vB.w;
    }
    a0 += b_ih[j_0] + b_hh[j_0];
    a1 += b_ih[j_0 + 1] + b_hh[j_0 + 1];

    const int lane = tid & 63;
    const int base = lane & ~3;
#pragma unroll
    for (int uu = 0; uu < 2; ++uu) {
        float g  = (uu == 0) ? a0 : a1;
        float gi = __shfl(g, base + 0, 64);
        float gf = __shfl(g, base + 1, 64);
        float gg = __shfl(g, base + 2, 64);
        float go = __shfl(g, base + 3, 64);
        if (q == uu) {
            const int u = u0 + uu;
            float i_ = 1.f / (1.f + expf(-gi));
            float f_ = 1.f / (1.f + expf(-gf));
            float o_ = 1.f / (1.f + expf(-go));
            float g_ = tanhf(gg);
            float cv = c_ws[b * HIDDEN + u];
            float c2 = f_ * cv + i_ * g_;
            float h2 = o_ * tanhf(c2);
            c_ws[b * HIDDEN + u]  = c2;
            h_out[b * HIDDEN + u] = h2;
            ushort_t hh = f2bf(h2);
            h_hi[b * HIDDEN + u] = hh;
            h_lo[b * HIDDEN + u] = f2bf(h2 - bf2f(hh));
        }
    }
}

// ---------- per-step fc: bf16-split MFMA, split-K x2 per tile, 4 waves/block ----------
// 250 blocks x 256 threads. Waves {0,1} -> tile 2*blk, waves {2,3} -> tile 2*blk+1.
// Within a pair, wave khalf handles K in [khalf*256, khalf*256+256). The khalf=1
// wave dumps acc to LDS in register-index space (layout-agnostic elementwise add);
// khalf=0 wave adds and runs the verified R5 epilogue.
__global__ __launch_bounds__(256) void fc_argmax(
    const ushort_t* __restrict__ h_hi, const ushort_t* __restrict__ h_lo,
    const ushort_t* __restrict__ Whi,  const ushort_t* __restrict__ Wlo,
    const float* __restrict__ b_fc,
    float* __restrict__ out,
    unsigned long long* __restrict__ part,
    int t)
{
    __shared__ float red[2][4096];

    const int tid = threadIdx.x;
    const int lane = tid & 63, wid = tid >> 6;
    const int tileSel = wid >> 1, khalf = wid & 1;
    const int tileIdx = blockIdx.x * 2 + tileSel;
    const int n0 = tileIdx * 64;
    const int r16 = lane & 15, g = lane >> 4;

    f32x4 acc[4][4];
#pragma unroll
    for (int i = 0; i < 4; ++i)
#pragma unroll
        for (int j = 0; j < 4; ++j) acc[i][j] = (f32x4){0.f, 0.f, 0.f, 0.f};

    const ushort_t* ha = h_hi + (size_t)r16 * EMBED + g * 8;
    const ushort_t* la = h_lo + (size_t)r16 * EMBED + g * 8;
    const ushort_t* hb = Whi + (size_t)(n0 + r16) * EMBED + g * 8;
    const ushort_t* lb = Wlo + (size_t)(n0 + r16) * EMBED + g * 8;

    const int kb0 = khalf * 8;
    for (int kb = kb0; kb < kb0 + 8; ++kb) {
        const int ko = kb * 32;
        bf16x8 Ah[4], Al[4], Bh[4], Bl[4];
#pragma unroll
        for (int mt = 0; mt < 4; ++mt) {
            Ah[mt] = *(const bf16x8*)(ha + (size_t)mt * 16 * EMBED + ko);
            Al[mt] = *(const bf16x8*)(la + (size_t)mt * 16 * EMBED + ko);
        }
#pragma unroll
        for (int nt = 0; nt < 4; ++nt) {
            Bh[nt] = *(const bf16x8*)(hb + (size_t)nt * 16 * EMBED + ko);
            Bl[nt] = *(const bf16x8*)(lb + (size_t)nt * 16 * EMBED + ko);
        }
#pragma unroll
        for (int mt = 0; mt < 4; ++mt)
#pragma unroll
            for (int nt = 0; nt < 4; ++nt) {
                acc[mt][nt] = __builtin_amdgcn_mfma_f32_16x16x32_bf16(Al[mt], Bh[nt], acc[mt][nt], 0, 0, 0);
                acc[mt][nt] = __builtin_amdgcn_mfma_f32_16x16x32_bf16(Ah[mt], Bl[nt], acc[mt][nt], 0, 0, 0);
                acc[mt][nt] = __builtin_amdgcn_mfma_f32_16x16x32_bf16(Ah[mt], Bh[nt], acc[mt][nt], 0, 0, 0);
            }
    }

    // pair-reduce: khalf=1 stores (reg-index space, stride-1 across lanes)
    if (khalf) {
#pragma unroll
        for (int mt = 0; mt < 4; ++mt)
#pragma unroll
            for (int nt = 0; nt < 4; ++nt)
#pragma unroll
                for (int reg = 0; reg < 4; ++reg)
                    red[tileSel][((mt * 4 + nt) * 4 + reg) * 64 + lane] = acc[mt][nt][reg];
    }
    __syncthreads();
    if (khalf) return;

#pragma unroll
    for (int mt = 0; mt < 4; ++mt)
#pragma unroll
        for (int nt = 0; nt < 4; ++nt)
#pragma unroll
            for (int reg = 0; reg < 4; ++reg)
                acc[mt][nt][reg] += red[tileSel][((mt * 4 + nt) * 4 + reg) * 64 + lane];

    // epilogue (verified in R4/R5): bias, NT store, per-row max-key -> part slot
    float bias[4];
#pragma unroll
    for (int nt = 0; nt < 4; ++nt) bias[nt] = b_fc[n0 + nt * 16 + r16];

#pragma unroll
    for (int mt = 0; mt < 4; ++mt)
#pragma unroll
        for (int reg = 0; reg < 4; ++reg) {
            const int row = mt * 16 + g * 4 + reg;
            float* op = &out[(size_t)row * (MAXLEN * VOCAB) + (size_t)(t + 1) * VOCAB];
            unsigned long long km = 0ull;
#pragma unroll
            for (int nt = 0; nt < 4; ++nt) {
                const int col = n0 + nt * 16 + r16;
                float v = acc[mt][nt][reg] + bias[nt];
                __builtin_nontemporal_store(v, op + col);
                unsigned long long kk = pack_key(v, col);
                km = kk > km ? kk : km;
            }
#pragma unroll
            for (int msk = 8; msk >= 1; msk >>= 1) {
                unsigned long long o = __shfl_xor(km, msk, 64);
                km = km > o ? km : o;
            }
            if (r16 == 0) part[(size_t)row * PSTRIDE + tileIdx] = km;
        }
}

extern "C" void kernel_launch(void* const* d_in, const int* in_sizes, int n_in,
                              void* d_out, int out_size, void* d_ws, size_t ws_size,
                              hipStream_t stream) {
    const float* enc       = (const float*)d_in[0];
    const int*   captions  = (const int*)  d_in[1];
    const float* emb       = (const float*)d_in[2];
    const float* W_ih      = (const float*)d_in[3];
    const float* b_ih      = (const float*)d_in[4];
    const float* W_hh      = (const float*)d_in[5];
    const float* b_hh      = (const float*)d_in[6];
    const float* W_fc      = (const float*)d_in[7];
    const float* b_fc      = (const float*)d_in[8];
    const float* W_init_h  = (const float*)d_in[9];
    const float* b_init_h  = (const float*)d_in[10];
    const float* W_init_c  = (const float*)d_in[11];
    const float* b_init_c  = (const float*)d_in[12];
    float* out = (float*)d_out;

    float* ws = (float*)d_ws;
    float* h0 = ws;                                          // 32768 f32
    float* h1 = ws + 32768;                                  // 32768 f32
    float* c  = ws + 65536;                                  // 32768 f32
    ushort_t* h_hi = (ushort_t*)(ws + 98560);                // 64*512 bf16
    ushort_t* h_lo = (ushort_t*)(ws + 114944);               // 64*512 bf16
    unsigned long long* part = (unsigned long long*)(ws + 131328); // 64*512 u64
    ushort_t* Whi  = (ushort_t*)(ws + 196864);               // 32000*512 bf16
    ushort_t* Wlo  = (ushort_t*)(ws + 8388864);              // 32000*512 bf16

    wsplit_kernel<<<2048, 256, 0, stream>>>(W_fc, Whi, Wlo);
    init_kernel<<<64, 256, 0, stream>>>(enc, W_init_h, b_init_h, W_init_c, b_init_c,
                                        h0, c, out);
    for (int t = 0; t < MAXLEN - 1; ++t) {
        float* hin  = (t & 1) ? h1 : h0;
        float* hout = (t & 1) ? h0 : h1;
        lstm_step<<<256, 256, 0, stream>>>(emb, W_ih, b_ih, W_hh, b_hh, captions,
                                           part, hin, hout, h_hi, h_lo, c, t);
        fc_argmax<<<NTILE / 2, 256, 0, stream>>>(h_hi, h_lo, Whi, Wlo, b_fc, out, part, t);
    }
}